// Round 8
// baseline (196.882 us; speedup 1.0000x reference)
//
#include <hip/hip_runtime.h>
#include <math.h>

typedef float    f32x16v __attribute__((ext_vector_type(16)));
typedef _Float16 f16x8   __attribute__((ext_vector_type(8)));
typedef _Float16 f16x2   __attribute__((ext_vector_type(2)));
typedef int      i32x2   __attribute__((ext_vector_type(2)));

#define GT_N 1024
#define GT_SCALE 102.3f          // 1/delta, delta = 10/1023
#define GT_DELTA (10.0f / 1023.0f)

// ---------------- featuremap repack: (4,H,W) -> (H,W,4) ----------------
__global__ void repack_fm_kernel(const float* __restrict__ fm,
                                 float4* __restrict__ out, int HW) {
    int idx = blockIdx.x * blockDim.x + threadIdx.x;
    if (idx >= HW) return;
    float4 v;
    v.x = fm[idx];
    v.y = fm[HW + idx];
    v.z = fm[2 * HW + idx];
    v.w = fm[3 * HW + idx];
    out[idx] = v;
}

// ---------------- exact-GELU table: 1024 x {g, dg} over [-5,5] ----------------
__global__ void build_gelu_table_kernel(float2* __restrict__ tbl) {
    int i = blockIdx.x * blockDim.x + threadIdx.x;
    if (i >= GT_N) return;
    float v0 = -5.0f + (float)i * GT_DELTA;
    float v1 = v0 + GT_DELTA;
    float g0 = 0.5f * v0 * (1.0f + erff(v0 * 0.70710678118654752440f));
    float g1 = 0.5f * v1 * (1.0f + erff(v1 * 0.70710678118654752440f));
    float2 e; e.x = g0; e.y = g1 - g0;
    tbl[i] = e;
}

// Fallback exact GELU (A&S 7.1.26 erfc), branchless.
__device__ __forceinline__ float gelu_as(float v) {
    float z = fabsf(v) * 0.70710678118654752440f;
    float t = __builtin_amdgcn_rcpf(fmaf(0.3275911f, z, 1.0f));
    float e = __expf(-z * z);
    float p = fmaf(1.061405429f, t, -1.453152027f);
    p = fmaf(p, t, 1.421413741f);
    p = fmaf(p, t, -0.284496736f);
    p = fmaf(p, t, 0.254829592f);
    p = p * t;
    float he = 0.5f * p * e;
    float phi = (v >= 0.0f) ? (1.0f - he) : he;
    return v * phi;
}

__device__ __forceinline__ float gelu_tbl(float v, const float2* __restrict__ gt) {
    float u = fminf(fmaxf(v, -5.0f), 5.0f);
    float t = (u + 5.0f) * GT_SCALE;
    float fi = floorf(t);
    int idx = (int)fi;
    float f = t - fi;
    float2 e = gt[idx];
    float g = fmaf(f, e.y, e.x);
    return (v > 5.0f) ? v : g;
}

// pack two f32 -> one u32 of two f16 (RNE via C cast semantics)
__device__ __forceinline__ unsigned pkrn(float a, float b) {
    union { f16x2 h; unsigned u; } cv;
    cv.h.x = (_Float16)a; cv.h.y = (_Float16)b;
    return cv.u;
}

__device__ __forceinline__ f16x8 frag4(unsigned w0, unsigned w1,
                                       unsigned w2, unsigned w3) {
    union { unsigned u[4]; f16x8 v; } cv;
    cv.u[0] = w0; cv.u[1] = w1; cv.u[2] = w2; cv.u[3] = w3;
    return cv.v;
}

// duplex half-wave exchange: a.hi <-> b.lo
__device__ __forceinline__ void swap32(unsigned &a, unsigned &b) {
    i32x2 r = __builtin_amdgcn_permlane32_swap((int)a, (int)b, false, false);
    a = (unsigned)r.x; b = (unsigned)r.y;
}

// A-fragment for mfma_32x32x16: lane holds row (lane&31), k = (lane>>5)*8 + e
__device__ __forceinline__ f16x8 load_wfrag(const float* __restrict__ Wm,
                                            int rows, int K, int lane) {
    int m = lane & 31, q = lane >> 5;
    int k0 = q * 8;
    f16x8 r;
    #pragma unroll
    for (int e = 0; e < 8; ++e) {
        int k = k0 + e;
        float v = (m < rows && k < K) ? Wm[m * K + k] : 0.0f;
        r[e] = (_Float16)v;
    }
    return r;
}

template <bool REPACKED, bool TABLE>
__global__ __launch_bounds__(256) void fused_mlp_kernel(
    const float* __restrict__ x,
    const float* __restrict__ fm,    // original (4,H,W), if !REPACKED
    const float4* __restrict__ fmr,  // repacked (H,W,4), if REPACKED
    const float2* __restrict__ gtab, // global gelu table, if TABLE
    const float* __restrict__ W1, const float* __restrict__ b1,
    const float* __restrict__ W2, const float* __restrict__ b2,
    const float* __restrict__ W3, const float* __restrict__ b3,
    const float* __restrict__ Wh, const float* __restrict__ bh,
    float* __restrict__ out, int B, int H, int W)
{
    __shared__ float2 gt[GT_N];
    if (TABLE) {
        int t = threadIdx.x;
        #pragma unroll
        for (int k = 0; k < GT_N / 256; ++k)
            gt[t + 256 * k] = gtab[t + 256 * k];
        __syncthreads();
    }

    int tid  = blockIdx.x * blockDim.x + threadIdx.x;
    int lane = threadIdx.x & 63;
    int q    = lane >> 5;
    int wbase = blockIdx.x * 256 + (threadIdx.x & ~63);
    int i = tid < B ? tid : B - 1;   // clamp (full wave participates in MFMA)

    // ---- weight A-fragments (f16, one-time divergent loads, cached) ----
    f16x8 w2f = load_wfrag(W2, 16, 16, lane);
    f16x8 w3f = load_wfrag(W3, 16, 16, lane);
    f16x8 whf = load_wfrag(Wh, 3, 16, lane);

    // ---- bias vectors matched to C-layout rows: j = (r&3)+8*(r>>2)+4q ----
    float b2v[8], b3v[8];
    #pragma unroll
    for (int r = 0; r < 8; ++r) {
        int jlo = (r & 3) + 8 * (r >> 2);
        b2v[r] = q ? b2[jlo + 4] : b2[jlo];
        b3v[r] = q ? b3[jlo + 4] : b3[jlo];
    }

    // ---- load x (3 floats, streaming) ----
    const float* xp = x + (size_t)i * 3;
    float xa = __builtin_nontemporal_load(xp + 0);
    float xb = __builtin_nontemporal_load(xp + 1);
    float xc = __builtin_nontemporal_load(xp + 2);

    // ---- bilinear sample (border padding, align_corners=False) ----
    float inp[8];
    {
        float gx = xa * 2.0f - 1.0f;
        float gy = xb * 2.0f - 1.0f;
        float ix = ((gx + 1.0f) * (float)W - 1.0f) * 0.5f;
        float iy = ((gy + 1.0f) * (float)H - 1.0f) * 0.5f;
        ix = fminf(fmaxf(ix, 0.0f), (float)(W - 1));
        iy = fminf(fmaxf(iy, 0.0f), (float)(H - 1));
        float x0f = floorf(ix), y0f = floorf(iy);
        float wx = ix - x0f, wy = iy - y0f;
        int x0 = (int)x0f, y0 = (int)y0f;
        int x1 = x0 + 1; if (x1 > W - 1) x1 = W - 1;
        int y1 = y0 + 1; if (y1 > H - 1) y1 = H - 1;

        float4 f00, f01, f10, f11;
        if (REPACKED) {
            f00 = fmr[y0 * W + x0];
            f01 = fmr[y0 * W + x1];
            f10 = fmr[y1 * W + x0];
            f11 = fmr[y1 * W + x1];
        } else {
            int HW = H * W;
            const float* c0 = fm;
            const float* c1 = fm + HW;
            const float* c2 = fm + 2 * HW;
            const float* c3 = fm + 3 * HW;
            int i00 = y0 * W + x0, i01 = y0 * W + x1;
            int i10 = y1 * W + x0, i11 = y1 * W + x1;
            f00 = make_float4(c0[i00], c1[i00], c2[i00], c3[i00]);
            f01 = make_float4(c0[i01], c1[i01], c2[i01], c3[i01]);
            f10 = make_float4(c0[i10], c1[i10], c2[i10], c3[i10]);
            f11 = make_float4(c0[i11], c1[i11], c2[i11], c3[i11]);
        }
        float omwx = 1.0f - wx, omwy = 1.0f - wy;
        float tx = f00.x * omwx + f01.x * wx, bx = f10.x * omwx + f11.x * wx;
        float ty = f00.y * omwx + f01.y * wx, by = f10.y * omwx + f11.y * wx;
        float tz = f00.z * omwx + f01.z * wx, bz = f10.z * omwx + f11.z * wx;
        float tw = f00.w * omwx + f01.w * wx, bw = f10.w * omwx + f11.w * wx;

        inp[0] = xa;
        inp[1] = xb;
        inp[2] = xc;
        inp[3] = tx * omwy + bx * wy;
        inp[4] = ty * omwy + by * wy;
        inp[5] = tz * omwy + bz * wy;
        inp[6] = tw * omwy + bw * wy;
        inp[7] = __expf(xc) - 1.0f;
    }

    // ---- layer 1: 8 -> 16, fp32 VALU (inputs stay exact), gelu ----
    float h1[16];
    #pragma unroll
    for (int j = 0; j < 16; ++j) {
        float acc = b1[j];
        #pragma unroll
        for (int k = 0; k < 8; ++k)
            acc = fmaf(W1[j * 8 + k], inp[k], acc);
        h1[j] = TABLE ? gelu_tbl(acc, gt) : gelu_as(acc);
    }

    // ---- transform h1 (point-per-lane) -> B-fragments for 2 tiles ----
    // tile0 = points wbase+0..31 (cols), tile1 = points wbase+32..63
    unsigned Cp[8];
    #pragma unroll
    for (int e = 0; e < 8; ++e) Cp[e] = pkrn(h1[2 * e], h1[2 * e + 1]);
    #pragma unroll
    for (int e = 0; e < 4; ++e) swap32(Cp[e], Cp[e + 4]);
    f16x8 bf0 = frag4(Cp[0], Cp[1], Cp[2], Cp[3]);
    f16x8 bf1 = frag4(Cp[4], Cp[5], Cp[6], Cp[7]);

    f32x16v zc;
    #pragma unroll
    for (int r = 0; r < 16; ++r) zc[r] = 0.0f;

    // ---- layer 2 (MFMA) + gelu + relayout ----
    f32x16v t0 = __builtin_amdgcn_mfma_f32_32x32x16_f16(w2f, bf0, zc, 0, 0, 0);
    f32x16v t1 = __builtin_amdgcn_mfma_f32_32x32x16_f16(w2f, bf1, zc, 0, 0, 0);
    unsigned P0[4], P1[4];
    #pragma unroll
    for (int e = 0; e < 4; ++e) {
        float a0 = t0[2 * e]     + b2v[2 * e];
        float a1 = t0[2 * e + 1] + b2v[2 * e + 1];
        float c0 = t1[2 * e]     + b2v[2 * e];
        float c1 = t1[2 * e + 1] + b2v[2 * e + 1];
        float g0 = TABLE ? gelu_tbl(a0, gt) : gelu_as(a0);
        float g1 = TABLE ? gelu_tbl(a1, gt) : gelu_as(a1);
        float g2 = TABLE ? gelu_tbl(c0, gt) : gelu_as(c0);
        float g3 = TABLE ? gelu_tbl(c1, gt) : gelu_as(c1);
        P0[e] = pkrn(g0, g1);
        P1[e] = pkrn(g2, g3);
    }
    swap32(P0[0], P0[2]); swap32(P0[1], P0[3]);
    swap32(P1[0], P1[2]); swap32(P1[1], P1[3]);
    bf0 = frag4(P0[0], P0[1], P0[2], P0[3]);
    bf1 = frag4(P1[0], P1[1], P1[2], P1[3]);

    // ---- layer 3 (MFMA) + gelu + relayout ----
    t0 = __builtin_amdgcn_mfma_f32_32x32x16_f16(w3f, bf0, zc, 0, 0, 0);
    t1 = __builtin_amdgcn_mfma_f32_32x32x16_f16(w3f, bf1, zc, 0, 0, 0);
    #pragma unroll
    for (int e = 0; e < 4; ++e) {
        float a0 = t0[2 * e]     + b3v[2 * e];
        float a1 = t0[2 * e + 1] + b3v[2 * e + 1];
        float c0 = t1[2 * e]     + b3v[2 * e];
        float c1 = t1[2 * e + 1] + b3v[2 * e + 1];
        float g0 = TABLE ? gelu_tbl(a0, gt) : gelu_as(a0);
        float g1 = TABLE ? gelu_tbl(a1, gt) : gelu_as(a1);
        float g2 = TABLE ? gelu_tbl(c0, gt) : gelu_as(c0);
        float g3 = TABLE ? gelu_tbl(c1, gt) : gelu_as(c1);
        P0[e] = pkrn(g0, g1);
        P1[e] = pkrn(g2, g3);
    }
    swap32(P0[0], P0[2]); swap32(P0[1], P0[3]);
    swap32(P1[0], P1[2]); swap32(P1[1], P1[3]);
    bf0 = frag4(P0[0], P0[1], P0[2], P0[3]);
    bf1 = frag4(P1[0], P1[1], P1[2], P1[3]);

    // ---- head (MFMA): rows 0..2 of C (at q==0) are out[0..2] ----
    t0 = __builtin_amdgcn_mfma_f32_32x32x16_f16(whf, bf0, zc, 0, 0, 0);
    t1 = __builtin_amdgcn_mfma_f32_32x32x16_f16(whf, bf1, zc, 0, 0, 0);

    if (lane < 32) {
        float bh0 = bh[0], bh1 = bh[1], bh2 = bh[2];
        int p0 = wbase + lane;
        int p1 = p0 + 32;
        if (p0 < B) {
            float* o = out + (size_t)p0 * 3;
            __builtin_nontemporal_store(t0[0] + bh0, o + 0);
            __builtin_nontemporal_store(t0[1] + bh1, o + 1);
            __builtin_nontemporal_store(t0[2] + bh2, o + 2);
        }
        if (p1 < B) {
            float* o = out + (size_t)p1 * 3;
            __builtin_nontemporal_store(t1[0] + bh0, o + 0);
            __builtin_nontemporal_store(t1[1] + bh1, o + 1);
            __builtin_nontemporal_store(t1[2] + bh2, o + 2);
        }
    }
}

extern "C" void kernel_launch(void* const* d_in, const int* in_sizes, int n_in,
                              void* d_out, int out_size, void* d_ws, size_t ws_size,
                              hipStream_t stream) {
    const float* x  = (const float*)d_in[0];
    const float* fm = (const float*)d_in[1];
    const float* W1 = (const float*)d_in[2];
    const float* b1 = (const float*)d_in[3];
    const float* W2 = (const float*)d_in[4];
    const float* b2 = (const float*)d_in[5];
    const float* W3 = (const float*)d_in[6];
    const float* b3 = (const float*)d_in[7];
    const float* Wh = (const float*)d_in[8];
    const float* bh = (const float*)d_in[9];
    float* out = (float*)d_out;

    int B  = in_sizes[0] / 3;
    int HW = in_sizes[1] / 4;
    int H = 1;
    while ((long long)(H + 1) * (H + 1) <= (long long)HW) ++H;  // integer sqrt
    int W = HW / H;

    size_t repack_bytes = (size_t)HW * sizeof(float4);
    size_t table_bytes  = (size_t)GT_N * sizeof(float2);

    bool repack, table;
    float4* fmr = nullptr;
    float2* gtab = nullptr;
    if (ws_size >= repack_bytes + table_bytes) {
        repack = true; table = true;
        fmr = (float4*)d_ws;
        gtab = (float2*)((char*)d_ws + repack_bytes);
    } else if (ws_size >= repack_bytes) {
        repack = true; table = false;
        fmr = (float4*)d_ws;
    } else if (ws_size >= table_bytes) {
        repack = false; table = true;
        gtab = (float2*)d_ws;
    } else {
        repack = false; table = false;
    }

    if (repack) {
        int blocks = (HW + 255) / 256;
        repack_fm_kernel<<<blocks, 256, 0, stream>>>(fm, fmr, HW);
    }
    if (table) {
        build_gelu_table_kernel<<<GT_N / 256, 256, 0, stream>>>(gtab);
    }

    int blocks = (B + 255) / 256;
    if (repack && table) {
        fused_mlp_kernel<true, true><<<blocks, 256, 0, stream>>>(
            x, fm, fmr, gtab, W1, b1, W2, b2, W3, b3, Wh, bh, out, B, H, W);
    } else if (repack) {
        fused_mlp_kernel<true, false><<<blocks, 256, 0, stream>>>(
            x, fm, fmr, gtab, W1, b1, W2, b2, W3, b3, Wh, bh, out, B, H, W);
    } else if (table) {
        fused_mlp_kernel<false, true><<<blocks, 256, 0, stream>>>(
            x, fm, fmr, gtab, W1, b1, W2, b2, W3, b3, Wh, bh, out, B, H, W);
    } else {
        fused_mlp_kernel<false, false><<<blocks, 256, 0, stream>>>(
            x, fm, fmr, gtab, W1, b1, W2, b2, W3, b3, Wh, bh, out, B, H, W);
    }
}

// Round 9
// 159.272 us; speedup vs baseline: 1.2361x; 1.2361x over previous
//
#include <hip/hip_runtime.h>
#include <math.h>

typedef _Float16 f16x2 __attribute__((ext_vector_type(2)));

#define GT_N 1024
#define GT_SCALE 102.3f          // 1/delta, delta = 10/1023
#define GT_DELTA (10.0f / 1023.0f)
#define NPAIR 280                // 128 (W2) + 128 (W3) + 24 (Wh) f16x2 pairs

// ---------------- featuremap repack: (4,H,W) -> (H,W,4) ----------------
__global__ void repack_fm_kernel(const float* __restrict__ fm,
                                 float4* __restrict__ out, int HW) {
    int idx = blockIdx.x * blockDim.x + threadIdx.x;
    if (idx >= HW) return;
    float4 v;
    v.x = fm[idx];
    v.y = fm[HW + idx];
    v.z = fm[2 * HW + idx];
    v.w = fm[3 * HW + idx];
    out[idx] = v;
}

// ---------------- exact-GELU table: 1024 x {g, dg} over [-5,5] ----------------
__global__ void build_gelu_table_kernel(float2* __restrict__ tbl) {
    int i = blockIdx.x * blockDim.x + threadIdx.x;
    if (i >= GT_N) return;
    float v0 = -5.0f + (float)i * GT_DELTA;
    float v1 = v0 + GT_DELTA;
    float g0 = 0.5f * v0 * (1.0f + erff(v0 * 0.70710678118654752440f));
    float g1 = 0.5f * v1 * (1.0f + erff(v1 * 0.70710678118654752440f));
    float2 e; e.x = g0; e.y = g1 - g0;
    tbl[i] = e;
}

// ---------------- pack W2/W3/Wh rows into f16 pairs (RNE) ----------------
__global__ void pack_weights_kernel(const float* __restrict__ W2,
                                    const float* __restrict__ W3,
                                    const float* __restrict__ Wh,
                                    unsigned* __restrict__ wp) {
    int t = blockIdx.x * blockDim.x + threadIdx.x;
    if (t >= NPAIR) return;
    float a, b;
    if (t < 128)      {              a = W2[2 * t];  b = W2[2 * t + 1]; }
    else if (t < 256) { int u = t - 128; a = W3[2 * u]; b = W3[2 * u + 1]; }
    else              { int u = t - 256; a = Wh[2 * u]; b = Wh[2 * u + 1]; }
    union { f16x2 h; unsigned u; } cv;
    cv.h.x = (_Float16)a; cv.h.y = (_Float16)b;
    wp[t] = cv.u;
}

// Fallback exact GELU (A&S 7.1.26 erfc), branchless.
__device__ __forceinline__ float gelu_as(float v) {
    float z = fabsf(v) * 0.70710678118654752440f;
    float t = __builtin_amdgcn_rcpf(fmaf(0.3275911f, z, 1.0f));
    float e = __expf(-z * z);
    float p = fmaf(1.061405429f, t, -1.453152027f);
    p = fmaf(p, t, 1.421413741f);
    p = fmaf(p, t, -0.284496736f);
    p = fmaf(p, t, 0.254829592f);
    p = p * t;
    float he = 0.5f * p * e;
    float phi = (v >= 0.0f) ? (1.0f - he) : he;
    return v * phi;
}

__device__ __forceinline__ float gelu_tbl(float v, const float2* __restrict__ gt) {
    float u = fminf(fmaxf(v, -5.0f), 5.0f);
    float t = (u + 5.0f) * GT_SCALE;
    float fi = floorf(t);
    int idx = (int)fi;
    float f = t - fi;
    float2 e = gt[idx];
    float g = fmaf(f, e.y, e.x);
    return (v > 5.0f) ? v : g;
}

__device__ __forceinline__ f16x2 pk(float a, float b) {
    f16x2 r; r.x = (_Float16)a; r.y = (_Float16)b; return r;
}

// ---------- bilinear sample + input-feature build (shared) ----------
template <bool REPACKED>
__device__ __forceinline__ void build_inp(
    float xa, float xb, float xc,
    const float* __restrict__ fm, const float4* __restrict__ fmr,
    int H, int W, float* inp)
{
    float gx = xa * 2.0f - 1.0f;
    float gy = xb * 2.0f - 1.0f;
    float ix = ((gx + 1.0f) * (float)W - 1.0f) * 0.5f;
    float iy = ((gy + 1.0f) * (float)H - 1.0f) * 0.5f;
    ix = fminf(fmaxf(ix, 0.0f), (float)(W - 1));
    iy = fminf(fmaxf(iy, 0.0f), (float)(H - 1));
    float x0f = floorf(ix), y0f = floorf(iy);
    float wx = ix - x0f, wy = iy - y0f;
    int x0 = (int)x0f, y0 = (int)y0f;
    int x1 = x0 + 1; if (x1 > W - 1) x1 = W - 1;
    int y1 = y0 + 1; if (y1 > H - 1) y1 = H - 1;

    float4 f00, f01, f10, f11;
    if (REPACKED) {
        f00 = fmr[y0 * W + x0];
        f01 = fmr[y0 * W + x1];
        f10 = fmr[y1 * W + x0];
        f11 = fmr[y1 * W + x1];
    } else {
        int HW = H * W;
        const float* c0 = fm;
        const float* c1 = fm + HW;
        const float* c2 = fm + 2 * HW;
        const float* c3 = fm + 3 * HW;
        int i00 = y0 * W + x0, i01 = y0 * W + x1;
        int i10 = y1 * W + x0, i11 = y1 * W + x1;
        f00 = make_float4(c0[i00], c1[i00], c2[i00], c3[i00]);
        f01 = make_float4(c0[i01], c1[i01], c2[i01], c3[i01]);
        f10 = make_float4(c0[i10], c1[i10], c2[i10], c3[i10]);
        f11 = make_float4(c0[i11], c1[i11], c2[i11], c3[i11]);
    }
    float omwx = 1.0f - wx, omwy = 1.0f - wy;
    float tx = f00.x * omwx + f01.x * wx, bx = f10.x * omwx + f11.x * wx;
    float ty = f00.y * omwx + f01.y * wx, by = f10.y * omwx + f11.y * wx;
    float tz = f00.z * omwx + f01.z * wx, bz = f10.z * omwx + f11.z * wx;
    float tw = f00.w * omwx + f01.w * wx, bw = f10.w * omwx + f11.w * wx;

    inp[0] = xa;
    inp[1] = xb;
    inp[2] = xc;
    inp[3] = tx * omwy + bx * wy;
    inp[4] = ty * omwy + by * wy;
    inp[5] = tz * omwy + bz * wy;
    inp[6] = tw * omwy + bw * wy;
    inp[7] = __expf(xc) - 1.0f;
}

// ---------------- FAST kernel: L1 fp32, L2/L3/head via v_dot2_f32_f16 ----------------
template <bool REPACKED>
__global__ __launch_bounds__(256) void fused_mlp_fast_kernel(
    const float* __restrict__ x,
    const float* __restrict__ fm,
    const float4* __restrict__ fmr,
    const float2* __restrict__ gtab,
    const f16x2* __restrict__ wpk,   // packed: W2[0,128) W3[128,256) Wh[256,280)
    const float* __restrict__ W1, const float* __restrict__ b1,
    const float* __restrict__ b2, const float* __restrict__ b3,
    const float* __restrict__ bh,
    float* __restrict__ out, int B, int H, int W)
{
    __shared__ float2 gt[GT_N];
    {
        int t = threadIdx.x;
        #pragma unroll
        for (int k = 0; k < GT_N / 256; ++k)
            gt[t + 256 * k] = gtab[t + 256 * k];
        __syncthreads();
    }

    int i = blockIdx.x * blockDim.x + threadIdx.x;
    if (i >= B) return;

    const float* xp = x + (size_t)i * 3;
    float xa = __builtin_nontemporal_load(xp + 0);
    float xb = __builtin_nontemporal_load(xp + 1);
    float xc = __builtin_nontemporal_load(xp + 2);

    float inp[8];
    build_inp<REPACKED>(xa, xb, xc, fm, fmr, H, W, inp);

    // ---- layer 1: 8 -> 16, fp32 FMA (weights scalarized), gelu -> f16 pairs ----
    f16x2 hp[8];
    #pragma unroll
    for (int e = 0; e < 8; ++e) {
        float a0 = b1[2 * e], a1 = b1[2 * e + 1];
        #pragma unroll
        for (int k = 0; k < 8; ++k) {
            a0 = fmaf(W1[(2 * e) * 8 + k], inp[k], a0);
            a1 = fmaf(W1[(2 * e + 1) * 8 + k], inp[k], a1);
        }
        hp[e] = pk(gelu_tbl(a0, gt), gelu_tbl(a1, gt));
    }

    // ---- layer 2: 16 -> 16 via dot2 ----
    f16x2 hq[8];
    #pragma unroll
    for (int e = 0; e < 8; ++e) {
        float a0 = b2[2 * e], a1 = b2[2 * e + 1];
        #pragma unroll
        for (int k = 0; k < 8; ++k) {
            a0 = __builtin_amdgcn_fdot2(hp[k], wpk[(2 * e) * 8 + k], a0, false);
            a1 = __builtin_amdgcn_fdot2(hp[k], wpk[(2 * e + 1) * 8 + k], a1, false);
        }
        hq[e] = pk(gelu_tbl(a0, gt), gelu_tbl(a1, gt));
    }

    // ---- layer 3: 16 -> 16 via dot2 ----
    #pragma unroll
    for (int e = 0; e < 8; ++e) {
        float a0 = b3[2 * e], a1 = b3[2 * e + 1];
        #pragma unroll
        for (int k = 0; k < 8; ++k) {
            a0 = __builtin_amdgcn_fdot2(hq[k], wpk[128 + (2 * e) * 8 + k], a0, false);
            a1 = __builtin_amdgcn_fdot2(hq[k], wpk[128 + (2 * e + 1) * 8 + k], a1, false);
        }
        hp[e] = pk(gelu_tbl(a0, gt), gelu_tbl(a1, gt));
    }

    // ---- head: 16 -> 3 via dot2 + store ----
    float o0 = bh[0], o1 = bh[1], o2 = bh[2];
    #pragma unroll
    for (int k = 0; k < 8; ++k) {
        o0 = __builtin_amdgcn_fdot2(hp[k], wpk[256 + 0 * 8 + k], o0, false);
        o1 = __builtin_amdgcn_fdot2(hp[k], wpk[256 + 1 * 8 + k], o1, false);
        o2 = __builtin_amdgcn_fdot2(hp[k], wpk[256 + 2 * 8 + k], o2, false);
    }
    float* op = out + (size_t)i * 3;
    __builtin_nontemporal_store(o0, op + 0);
    __builtin_nontemporal_store(o1, op + 1);
    __builtin_nontemporal_store(o2, op + 2);
}

// ---------------- legacy fp32 kernel (fallback if ws too small) ----------------
template <bool REPACKED>
__global__ __launch_bounds__(256) void fused_mlp_kernel(
    const float* __restrict__ x,
    const float* __restrict__ fm,
    const float4* __restrict__ fmr,
    const float* __restrict__ W1, const float* __restrict__ b1,
    const float* __restrict__ W2, const float* __restrict__ b2,
    const float* __restrict__ W3, const float* __restrict__ b3,
    const float* __restrict__ Wh, const float* __restrict__ bh,
    float* __restrict__ out, int B, int H, int W)
{
    int i = blockIdx.x * blockDim.x + threadIdx.x;
    if (i >= B) return;

    const float* xp = x + (size_t)i * 3;
    float xa = __builtin_nontemporal_load(xp + 0);
    float xb = __builtin_nontemporal_load(xp + 1);
    float xc = __builtin_nontemporal_load(xp + 2);

    float inp[8];
    build_inp<REPACKED>(xa, xb, xc, fm, fmr, H, W, inp);

    float h1[16];
    #pragma unroll
    for (int j = 0; j < 16; ++j) {
        float acc = b1[j];
        #pragma unroll
        for (int k = 0; k < 8; ++k) acc = fmaf(W1[j * 8 + k], inp[k], acc);
        h1[j] = gelu_as(acc);
    }
    float h2[16];
    #pragma unroll
    for (int j = 0; j < 16; ++j) {
        float acc = b2[j];
        #pragma unroll
        for (int k = 0; k < 16; ++k) acc = fmaf(W2[j * 16 + k], h1[k], acc);
        h2[j] = gelu_as(acc);
    }
    float h3[16];
    #pragma unroll
    for (int j = 0; j < 16; ++j) {
        float acc = b3[j];
        #pragma unroll
        for (int k = 0; k < 16; ++k) acc = fmaf(W3[j * 16 + k], h2[k], acc);
        h3[j] = gelu_as(acc);
    }
    float* op = out + (size_t)i * 3;
    #pragma unroll
    for (int c = 0; c < 3; ++c) {
        float acc = bh[c];
        #pragma unroll
        for (int k = 0; k < 16; ++k) acc = fmaf(Wh[c * 16 + k], h3[k], acc);
        __builtin_nontemporal_store(acc, op + c);
    }
}

extern "C" void kernel_launch(void* const* d_in, const int* in_sizes, int n_in,
                              void* d_out, int out_size, void* d_ws, size_t ws_size,
                              hipStream_t stream) {
    const float* x  = (const float*)d_in[0];
    const float* fm = (const float*)d_in[1];
    const float* W1 = (const float*)d_in[2];
    const float* b1 = (const float*)d_in[3];
    const float* W2 = (const float*)d_in[4];
    const float* b2 = (const float*)d_in[5];
    const float* W3 = (const float*)d_in[6];
    const float* b3 = (const float*)d_in[7];
    const float* Wh = (const float*)d_in[8];
    const float* bh = (const float*)d_in[9];
    float* out = (float*)d_out;

    int B  = in_sizes[0] / 3;
    int HW = in_sizes[1] / 4;
    int H = 1;
    while ((long long)(H + 1) * (H + 1) <= (long long)HW) ++H;  // integer sqrt
    int W = HW / H;

    size_t repack_bytes = (size_t)HW * sizeof(float4);
    size_t table_bytes  = (size_t)GT_N * sizeof(float2);
    size_t wpk_bytes    = (size_t)NPAIR * sizeof(unsigned);

    int blocks = (B + 255) / 256;

    if (ws_size >= repack_bytes + table_bytes + wpk_bytes) {
        // FAST path with repacked featuremap
        float4* fmr  = (float4*)d_ws;
        float2* gtab = (float2*)((char*)d_ws + repack_bytes);
        unsigned* wp = (unsigned*)((char*)d_ws + repack_bytes + table_bytes);
        repack_fm_kernel<<<(HW + 255) / 256, 256, 0, stream>>>(fm, fmr, HW);
        build_gelu_table_kernel<<<GT_N / 256, 256, 0, stream>>>(gtab);
        pack_weights_kernel<<<2, 256, 0, stream>>>(W2, W3, Wh, wp);
        fused_mlp_fast_kernel<true><<<blocks, 256, 0, stream>>>(
            x, fm, fmr, gtab, (const f16x2*)wp, W1, b1, b2, b3, bh, out, B, H, W);
    } else if (ws_size >= table_bytes + wpk_bytes) {
        // FAST path, direct featuremap layout
        float2* gtab = (float2*)d_ws;
        unsigned* wp = (unsigned*)((char*)d_ws + table_bytes);
        build_gelu_table_kernel<<<GT_N / 256, 256, 0, stream>>>(gtab);
        pack_weights_kernel<<<2, 256, 0, stream>>>(W2, W3, Wh, wp);
        fused_mlp_fast_kernel<false><<<blocks, 256, 0, stream>>>(
            x, fm, nullptr, gtab, (const f16x2*)wp, W1, b1, b2, b3, bh, out, B, H, W);
    } else if (ws_size >= repack_bytes) {
        float4* fmr = (float4*)d_ws;
        repack_fm_kernel<<<(HW + 255) / 256, 256, 0, stream>>>(fm, fmr, HW);
        fused_mlp_kernel<true><<<blocks, 256, 0, stream>>>(
            x, fm, fmr, W1, b1, W2, b2, W3, b3, Wh, bh, out, B, H, W);
    } else {
        fused_mlp_kernel<false><<<blocks, 256, 0, stream>>>(
            x, fm, nullptr, W1, b1, W2, b2, W3, b3, Wh, bh, out, B, H, W);
    }
}